// Round 14
// baseline (1416.363 us; speedup 1.0000x reference)
//
#include <hip/hip_runtime.h>

// Problem constants
#define BTOT 1024
#define TPTS 96
#define NV   7
#define HD   64
#define NH   256

typedef short bf16x8 __attribute__((ext_vector_type(8)));
typedef float f32x4  __attribute__((ext_vector_type(4)));
typedef unsigned int u32x4 __attribute__((ext_vector_type(4)));
#define MFMA16(a,b,c) __builtin_amdgcn_mfma_f32_16x16x32_bf16(a,b,c,0,0,0)

// LDS layout (32-bit word offsets), total 28368 words = 113472 B (1 block/CU)
#define OFF_YP    0       // 2 planes x [16 rows][32 words], XOR-swizzled   = 1024
#define OFF_TP    1024    // 2 planes x [16 rows][128 words], XOR-swizzled  = 4096
#define OFF_W2LO  5120    // W2 lo bf16 plane [64 o][128 w], swizzled       = 8192
#define OFF_YF    13312   // f32 [16][65] (decode only, commit writes)      = 1040
#define OFF_PS    14352   // f32 [4 nt][16 rows] row-sum partials           = 64
#define OFF_TPS   14416   // 96
#define OFF_DW1   14512   // f32 [3][64][64] decode layer-1                 = 12288
#define OFF_DW2   26800   // f32 [3][64][7]                                 = 1344
#define OFF_DB1   28144   // 192
#define OFF_DB2   28336   // 32 (21 used)
#define SMEM_WORDS 28368
#define SMEM_BYTES (SMEM_WORDS*4)

__device__ __forceinline__ float rdlane(float v, int i) {
    return __int_as_float(__builtin_amdgcn_readlane(__float_as_int(v), i));
}
__device__ __forceinline__ float wsum64(float v) {
    v += __shfl_xor(v, 1);  v += __shfl_xor(v, 2);  v += __shfl_xor(v, 4);
    v += __shfl_xor(v, 8);  v += __shfl_xor(v, 16); v += __shfl_xor(v, 32);
    return v;
}
__device__ __forceinline__ float tanh_fast(float x) {
    float e = __expf(2.f * x);
    return 1.f - 2.f / (e + 1.f);
}
__device__ __forceinline__ ushort bf16rn(float x) {
    unsigned u = __float_as_uint(x);
    return (ushort)((u + 0x7fffu + ((u >> 16) & 1u)) >> 16);
}
// 2-term round-to-nearest bf16 decomposition: x ~= h + l, error ~2^-18 rel
__device__ __forceinline__ void split2(float x, ushort& h, ushort& l) {
    h = bf16rn(x);
    float hf = __uint_as_float(((unsigned)h) << 16);
    l = bf16rn(x - hf);
}

union FU { u32x4 uv; unsigned u[4]; ushort s[8]; bf16x8 v; };

// 8 waves/block; 4 batch elements (rows 0-11 real, 12-15 ghost pad); grid 256.
// TWO barriers per ODE eval, NO partial exchange:
//   g1: wave w -> N-tiles {2w,2w+1} of GEMM1 (W1 frags in regs), writes T planes. B1.
//   g2: EVERY wave computes its nt (=w&3) tile over the FULL K=256 in-wave
//       (W2-hi full-K in 32 VGPR, W2-lo streamed from LDS plane), so dd is
//       complete per-wave; update state, publish Y planes + PS. B2.
// 124-VGPR budget via __launch_bounds__(512,2) (2nd arg = min BLOCKS/CU).
__global__ __launch_bounds__(512, 2)
void node_mfma14(const float* __restrict__ x,
                 const float* __restrict__ iw1, const float* __restrict__ ib1,
                 const float* __restrict__ iw2, const float* __restrict__ ib2,
                 const float* __restrict__ ow1, const float* __restrict__ ob1,
                 const float* __restrict__ ow2, const float* __restrict__ ob2,
                 const float* __restrict__ inter, const float* __restrict__ cons,
                 const float* __restrict__ dw1, const float* __restrict__ db1,
                 const float* __restrict__ dw2, const float* __restrict__ db2,
                 const float* __restrict__ tpts,
                 float* __restrict__ out)
{
    extern __shared__ float sm[];
    unsigned* YPw = (unsigned*)(sm + OFF_YP);    // hi [16][32]; lo at +512
    unsigned* TPw = (unsigned*)(sm + OFF_TP);    // hi [16][128]; lo at +2048
    unsigned* W2L = (unsigned*)(sm + OFF_W2LO);  // lo plane [64][128]
    float*    Yf  = sm + OFF_YF;
    float*    PS  = sm + OFF_PS;
    float*    tps = sm + OFF_TPS;
    float*    DW1 = sm + OFF_DW1;
    float*    DW2 = sm + OFF_DW2;
    float*    DB1 = sm + OFF_DB1;
    float*    DB2 = sm + OFF_DB2;

    const int tid = threadIdx.x;
    const int w   = tid >> 6;       // wave 0..7
    const int ln  = tid & 63;
    const int m   = ln & 15;        // tile row/col index
    const int g4  = ln >> 4;        // quad 0..3
    const int nt  = w & 3;          // GEMM2 N-tile / state tile
    const int kh  = w >> 2;         // publish row-slice (redundancy split)

    // ---- stage decode weights + t into LDS ----
    for (int idx = tid; idx < 3*HD*HD; idx += 512) DW1[idx] = dw1[idx];
    if (tid < 3*HD)  { for (int v = 0; v < NV; ++v) DW2[tid*NV + v] = dw2[tid*NV + v]; }
    if (tid < 192)   DB1[tid] = db1[tid];
    if (tid < 21)    DB2[tid] = db2[tid];
    if (tid < TPTS)  tps[tid] = tpts[tid];

    // ---- stage W2 LO plane, swizzled (granule gi=k>>3 XOR (o&31)) ----
    {
        ushort* W2Lu = (ushort*)W2L;
        for (int idx = tid; idx < NH*HD; idx += 512) {
            int k = idx >> 6, o = idx & 63;              // ow2[k][o]
            ushort h, l; split2(ow2[idx], h, l);
            int gi = k >> 3;
            int word = o*128 + ((((unsigned)(gi ^ (o & 31))) & 31) << 2) + ((k >> 1) & 3);
            W2Lu[word*2 + (k & 1)] = l;
        }
    }

    // ---- per-wave weight fragments in registers ----
    FU w1h[2][2], w1l[2][2];        // GEMM1: [tile u][cc]  (32 VGPR)
    FU w2h[8];                      // GEMM2 hi, FULL K=256 (32 VGPR)
    #pragma unroll
    for (int u = 0; u < 2; ++u)
        #pragma unroll
        for (int cc = 0; cc < 2; ++cc)
            #pragma unroll
            for (int j = 0; j < 8; ++j) {
                ushort h, l;
                int k1 = 32*cc + 8*g4 + j;
                split2(ow1[k1*NH + 16*(2*w+u) + m], h, l);
                w1h[u][cc].s[j] = h; w1l[u][cc].s[j] = l;
            }
    #pragma unroll
    for (int cc = 0; cc < 8; ++cc)
        #pragma unroll
        for (int j = 0; j < 8; ++j) {
            ushort h, l;
            int k2 = 32*cc + 8*g4 + j;
            split2(ow2[k2*HD + 16*nt + m], h, l);
            w2h[cc].s[j] = h;
        }
    float w64c[2], w65c[2], b1c[2];
    #pragma unroll
    for (int u = 0; u < 2; ++u) {
        int c1 = 16*(2*w+u) + m;
        w64c[u] = ow1[64*NH + c1];
        w65c[u] = ow1[65*NH + c1];
        b1c[u]  = ob1[c1];
    }
    const float b2c = ob2[16*nt + m];

    // M = conservation @ interaction, scaled 1/64; per-lane row cpm = m%3
    const int cpm = m % 3, base3 = m - cpm;
    float Mr0, Mr1, Mr2;
    {
        float I[9], C[9];
        #pragma unroll
        for (int i = 0; i < 9; ++i) { I[i] = inter[i]; C[i] = cons[i]; }
        float M_[3][3];
        #pragma unroll
        for (int r = 0; r < 3; ++r)
            #pragma unroll
            for (int c = 0; c < 3; ++c)
                M_[r][c] = (C[r*3+0]*I[0*3+c] + C[r*3+1]*I[1*3+c] + C[r*3+2]*I[2*3+c]) * (1.f/64.f);
        Mr0 = (cpm==0) ? M_[0][0] : (cpm==1) ? M_[1][0] : M_[2][0];
        Mr1 = (cpm==0) ? M_[0][1] : (cpm==1) ? M_[1][1] : M_[2][1];
        Mr2 = (cpm==0) ? M_[0][2] : (cpm==1) ? M_[1][2] : M_[2][2];
    }

    // ---- initial state y0: waves {2e,2e+1} redundantly compute element e ----
    {
        const int el0 = w >> 1;                 // 0..3
        const int b0  = blockIdx.x*4 + el0;
        float xs0,xs1,xs2,xs3,xs4,xs5,xs6;
        {
            const float* xp = x + (size_t)b0 * TPTS * NV + ln * NV;
            float v0=xp[0],v1=xp[1],v2=xp[2],v3=xp[3],v4=xp[4],v5=xp[5],v6=xp[6];
            if (ln < 32) {
                const float* xp2 = xp + 64 * NV;
                v0+=xp2[0]; v1+=xp2[1]; v2+=xp2[2]; v3+=xp2[3]; v4+=xp2[4]; v5+=xp2[5]; v6+=xp2[6];
            }
            xs0=wsum64(v0)*(1.f/96.f); xs1=wsum64(v1)*(1.f/96.f); xs2=wsum64(v2)*(1.f/96.f);
            xs3=wsum64(v3)*(1.f/96.f); xs4=wsum64(v4)*(1.f/96.f); xs5=wsum64(v5)*(1.f/96.f);
            xs6=wsum64(v6)*(1.f/96.f);
        }
        float h0v;
        {
            float a = ib1[ln];
            a = fmaf(xs0, iw1[0*HD+ln], a); a = fmaf(xs1, iw1[1*HD+ln], a);
            a = fmaf(xs2, iw1[2*HD+ln], a); a = fmaf(xs3, iw1[3*HD+ln], a);
            a = fmaf(xs4, iw1[4*HD+ln], a); a = fmaf(xs5, iw1[5*HD+ln], a);
            a = fmaf(xs6, iw1[6*HD+ln], a);
            h0v = fmaxf(a, 0.f);
        }
        float y0a = ib2[ln], y0b = ib2[64+ln], y0c = ib2[128+ln];
        #pragma unroll
        for (int k = 0; k < 64; ++k) {
            float hk = rdlane(h0v, k);
            y0a = fmaf(hk, iw2[k*192 + ln],       y0a);
            y0b = fmaf(hk, iw2[k*192 + 64 + ln],  y0b);
            y0c = fmaf(hk, iw2[k*192 + 128 + ln], y0c);
        }
        if ((w & 1) == 0) {           // waves 0,2,4,6: publish element el0 (rows 3el0..3el0+2)
            float yv[3] = {y0a, y0b, y0c};
            #pragma unroll
            for (int r = 0; r < 3; ++r) {
                int row = el0*3 + r;
                Yf[row*65 + ln] = yv[r];
                ushort hs, ls; split2(yv[r], hs, ls);
                unsigned hp = hs, lp = ls;
                unsigned hq = __shfl_xor(hp, 1), lq = __shfl_xor(lp, 1);
                if ((ln & 1) == 0) {
                    int wgrp = ln >> 3;
                    int woff = row*32 + ((((unsigned)(wgrp ^ row)) & 7) << 2) + ((ln >> 1) & 3);
                    YPw[woff]       = hp | (hq << 16);
                    YPw[512 + woff] = lp | (lq << 16);
                }
            }
            float S0 = wsum64(y0a), S1 = wsum64(y0b), S2 = wsum64(y0c);
            if (ln < 3) PS[el0*3 + ln] = (ln==0)?S0:(ln==1)?S1:S2;
        }
        if (w == 1 && ln < 48) PS[16 + ln] = 0.f;         // slots 1-3 fully zero
        if (w == 5 && ln >= 12 && ln < 16) PS[ln] = 0.f;  // slot 0 ghost rows
        if (w == 3) {                                      // zero ghost rows 12-15 of Y planes
            YPw[384 + ln] = 0u; YPw[448 + ln] = 0u;
            YPw[896 + ln] = 0u; YPw[960 + ln] = 0u;
        }
        if (w == 7) {                                      // zero ghost rows 12-15 of Yf
            #pragma unroll
            for (int r = 12; r < 16; ++r) Yf[r*65 + ln] = 0.f;
        }
    }
    __syncthreads();

    // state fragments, replicated in all waves (bitwise-identical per nt)
    f32x4 yb, ks;
    #pragma unroll
    for (int r = 0; r < 4; ++r) yb[r] = Yf[(4*g4 + r)*65 + 16*nt + m];

    // ---- publish (all waves): rows r = 2kh, 2kh+1 of this wave's fragment ----
    auto publish = [&](f32x4 ys, bool commit) {
        #pragma unroll
        for (int rr = 0; rr < 2; ++rr) {
            float yv = kh ? (rr ? ys[3] : ys[2]) : (rr ? ys[1] : ys[0]);
            const int row = 4*g4 + 2*kh + rr;
            ushort hs, ls; split2(yv, hs, ls);
            unsigned hp = hs, lp = ls;
            unsigned hq = __shfl_xor(hp, 1), lq = __shfl_xor(lp, 1);
            if ((m & 1) == 0) {
                int wgrp = 2*nt + (m >> 3);
                int woff = row*32 + ((((unsigned)(wgrp ^ row)) & 7) << 2) + ((m >> 1) & 3);
                YPw[woff]       = hp | (hq << 16);
                YPw[512 + woff] = lp | (lq << 16);
            }
            if (commit) Yf[row*65 + 16*nt + m] = yv;
            float s = yv;
            s += __shfl_xor(s, 1); s += __shfl_xor(s, 2);
            s += __shfl_xor(s, 4); s += __shfl_xor(s, 8);
            if (m == 0) PS[nt*16 + row] = s;
        }
    };

    // ---- one ODE-func eval: g1 -> B1 -> g2(full-K, in-wave dd). Caller adds B2. ----
    auto evalf = [&](float ts, f32x4& dd) {
        // interaction effect from row-sum partials
        float rsum = (PS[m] + PS[16+m]) + (PS[32+m] + PS[48+m]);
        float eAll = Mr0*__shfl(rsum, base3) + Mr1*__shfl(rsum, base3+1) + Mr2*__shfl(rsum, base3+2);

        // GEMM1 (K=64), two N-tiles sharing the A-fragments
        f32x4 aA0 = {0,0,0,0}, aB0 = {0,0,0,0}, aA1 = {0,0,0,0}, aB1 = {0,0,0,0};
        #pragma unroll
        for (int cc = 0; cc < 2; ++cc) {
            FU ah, al;
            int aoff = m*32 + ((((unsigned)((4*cc + g4) ^ m)) & 7) << 2);
            ah.uv = *(const u32x4*)(YPw + aoff);
            al.uv = *(const u32x4*)(YPw + 512 + aoff);
            aA0 = MFMA16(ah.v, w1h[0][cc].v, aA0);
            aB0 = MFMA16(ah.v, w1l[0][cc].v, aB0);
            aA0 = MFMA16(al.v, w1h[0][cc].v, aA0);
            aA1 = MFMA16(ah.v, w1h[1][cc].v, aA1);
            aB1 = MFMA16(ah.v, w1l[1][cc].v, aB1);
            aA1 = MFMA16(al.v, w1h[1][cc].v, aA1);
        }
        // epilogue: +ie +t +bias, tanh, split, publish T planes
        #pragma unroll
        for (int r = 0; r < 4; ++r) {
            float er = __shfl(eAll, 4*g4 + r);
            const int row = 4*g4 + r;
            #pragma unroll
            for (int u = 0; u < 2; ++u) {
                float val = u ? (aA1[r] + aB1[r]) : (aA0[r] + aB0[r]);
                val = fmaf(w64c[u], er, val);
                val = fmaf(w65c[u], ts, val);
                val += b1c[u];
                float th = tanh_fast(val);
                ushort hs, ls; split2(th, hs, ls);
                unsigned hp = hs, lp = ls;
                unsigned hq = __shfl_xor(hp, 1), lq = __shfl_xor(lp, 1);
                if ((m & 1) == 0) {
                    int wgrp = 4*w + 2*u + (m >> 3);
                    int woff = row*128 + ((((unsigned)wgrp & 24) | (((unsigned)(wgrp ^ row)) & 7)) << 2)
                             + ((m >> 1) & 3);
                    TPw[woff]        = hp | (hq << 16);
                    TPw[2048 + woff] = lp | (lq << 16);
                }
            }
        }
        __syncthreads();   // B1: T planes ready

        // GEMM2, FULL K=256, in-wave: A hi/lo from T planes, B hi from regs, B lo from LDS
        f32x4 pA = {0,0,0,0}, pB = {0,0,0,0};
        const int o = 16*nt + m;
        #pragma unroll
        for (int cc = 0; cc < 8; ++cc) {
            FU ah, al, bl;
            int G = 4*cc + g4;
            int aoff = m*128 + ((((unsigned)G & 24) | (((unsigned)(G ^ m)) & 7)) << 2);
            ah.uv = *(const u32x4*)(TPw + aoff);
            al.uv = *(const u32x4*)(TPw + 2048 + aoff);
            int woff = o*128 + ((((unsigned)(G ^ (o & 31))) & 31) << 2);
            bl.uv = *(const u32x4*)(W2L + woff);
            pA = MFMA16(ah.v, w2h[cc].v, pA);
            pB = MFMA16(ah.v, bl.v, pB);
            pA = MFMA16(al.v, w2h[cc].v, pA);
        }
        f32x4 qq = pA + pB;
        dd[0] = qq[0] + b2c; dd[1] = qq[1] + b2c;
        dd[2] = qq[2] + b2c; dd[3] = qq[3] + b2c;
    };

    // ---- decode one (cc,el) row from committed Yf, LDS weights, reg-broadcast y ----
    auto decode_row = [&](int row, int tix) {
        const int cc = row % 3, el = row / 3;
        const int b  = blockIdx.x*4 + el;
        float dyv = Yf[row*65 + ln];
        float acc = DB1[cc*HD + ln];
        #pragma unroll 8
        for (int h = 0; h < 64; ++h)
            acc = fmaf(rdlane(dyv, h), DW1[(cc*HD + h)*HD + ln], acc);
        float hid = fmaxf(acc, 0.f);
        #pragma unroll
        for (int v = 0; v < NV; ++v) {
            float pv = wsum64(hid * DW2[(cc*HD + ln)*NV + v]);
            if (ln == 0)
                out[(((size_t)cc*BTOT + b)*TPTS + tix)*NV + v] = pv + DB2[cc*NV + v];
        }
    };
    auto decode = [&](int tix) {
        decode_row(w, tix);                 // rows 0-7
        if (w < 4) decode_row(w + 8, tix);  // rows 8-11
    };

    // ---- RK4 over 95 intervals; 2 barriers per eval ----
    decode(0);
    f32x4 dd;
    #pragma unroll 1
    for (int s = 0; s < TPTS - 1; ++s) {
        const float ta = tps[s], tb = tps[s + 1];
        const float dt = tb - ta, hdt = 0.5f * dt;

        evalf(ta, dd);
        ks = dd; publish(yb + hdt*dd, false);
        __syncthreads();   // B2: Y planes / PS ready

        evalf(ta + hdt, dd);
        ks += 2.f*dd; publish(yb + hdt*dd, false);
        __syncthreads();

        evalf(ta + hdt, dd);
        ks += 2.f*dd; publish(yb + dt*dd, false);
        __syncthreads();

        evalf(tb, dd);
        ks += dd; yb = yb + (dt*(1.f/6.f))*ks; publish(yb, true);
        __syncthreads();

        decode(s + 1);
    }
}

extern "C" void kernel_launch(void* const* d_in, const int* in_sizes, int n_in,
                              void* d_out, int out_size, void* d_ws, size_t ws_size,
                              hipStream_t stream) {
    const float* x     = (const float*)d_in[0];
    const float* iw1   = (const float*)d_in[1];
    const float* ib1   = (const float*)d_in[2];
    const float* iw2   = (const float*)d_in[3];
    const float* ib2   = (const float*)d_in[4];
    const float* ow1   = (const float*)d_in[5];
    const float* ob1   = (const float*)d_in[6];
    const float* ow2   = (const float*)d_in[7];
    const float* ob2   = (const float*)d_in[8];
    const float* inter = (const float*)d_in[9];
    const float* cons  = (const float*)d_in[10];
    const float* dw1   = (const float*)d_in[11];
    const float* db1   = (const float*)d_in[12];
    const float* dw2   = (const float*)d_in[13];
    const float* db2   = (const float*)d_in[14];
    const float* tpts  = (const float*)d_in[15];
    float* out = (float*)d_out;

    // dynamic LDS > 64 KB (host-side, graph-capture safe)
    (void)hipFuncSetAttribute((const void*)node_mfma14,
                              hipFuncAttributeMaxDynamicSharedMemorySize,
                              SMEM_BYTES);

    node_mfma14<<<BTOT / 4, 512, SMEM_BYTES, stream>>>(
        x, iw1, ib1, iw2, ib2, ow1, ob1, ow2, ob2,
        inter, cons, dw1, db1, dw2, db2, tpts, out);
}